// Round 4
// baseline (204.330 us; speedup 1.0000x reference)
//
#include <hip/hip_runtime.h>

// WindowAttention fused kernel, MI355X gfx950 — round 4.
// Per window b (2048 windows, N=49 tokens padded->64, C=192, 6 heads x 32):
//   qkv = x @ qkv_w + b; S = scale*q k^T + mask[b%64]; softmax; o = P v; out = o @ proj_w + b
// 6 waves/block, wave h owns head h. Changes vs R3:
//  - q,k,v computed in ONE merged GEMM pass (acc[4][6]): 24 xs A-frag reads per
//    wave instead of 72; 144 back-to-back MFMAs.
//  - xs stores 49 real rows + one shared zero row ([50][200]); pad A-rows clamp
//    to the zero row. Block LDS 47648 B -> 3 blocks/CU (18 waves/CU).
//  - vT pitch 68 (conflict-free vb reads); pad attn_out writes skipped.

#define DIMC 192
#define NHEAD 6
#define HD 32
#define NTOK 49
#define NWIN 64
#define SCALE 0.17677669529663687f  // 1/sqrt(32)
#define XP 200   // xs pitch (shorts), [50][200]
#define QKP 36   // q/k/P transpose pitch
#define VP 68    // vT pitch

typedef short bf16x8 __attribute__((ext_vector_type(8)));
typedef short bf16x4 __attribute__((ext_vector_type(4)));
typedef short short4v __attribute__((ext_vector_type(4)));
typedef float f32x4 __attribute__((ext_vector_type(4)));

__device__ __forceinline__ short f2bs(float f) {
    // round-to-nearest-even fp32 -> bf16
    unsigned u = __builtin_bit_cast(unsigned, f);
    u = (u + 0x7fffu + ((u >> 16) & 1u)) >> 16;
    return (short)(unsigned short)u;
}

// 8-bf16 fragment load from 8B-aligned LDS
__device__ __forceinline__ bf16x8 ld8(const short* p) {
    bf16x4 lo = *reinterpret_cast<const bf16x4*>(p);
    bf16x4 hi = *reinterpret_cast<const bf16x4*>(p + 4);
    return __builtin_shufflevector(lo, hi, 0, 1, 2, 3, 4, 5, 6, 7);
}

__global__ void prep_weights(const float* __restrict__ qkv_w,
                             const float* __restrict__ proj_w,
                             short* __restrict__ wT, short* __restrict__ pT) {
    int i = blockIdx.x * 256 + threadIdx.x;
    if (i < DIMC * 3 * DIMC) {  // qkv_w [192][576] -> wT [576][192] bf16
        int k = i / (3 * DIMC), c = i - k * (3 * DIMC);
        wT[c * DIMC + k] = f2bs(qkv_w[i]);
    }
    if (i < DIMC * DIMC) {      // proj_w [192][192] -> pT [192][192] bf16 (transposed)
        int k = i / DIMC, c = i - k * DIMC;
        pT[c * DIMC + k] = f2bs(proj_w[i]);
    }
}

// LDS (shorts): xs [50][200] @ 0 (10000) ; per-wave scratch 2304 @ 10000 + wv*2304
//   scratch sequential reuse: q[64][36] -> k[64][36] -> vT[32][68] -> P halves [64][36]
// total 23824 shorts = 47648 B  => 3 blocks/CU (142.9 KB)

__global__ __launch_bounds__(384, 4)
void win_attn(const float* __restrict__ x, const float* __restrict__ mask,
              const float* __restrict__ qkv_b, const float* __restrict__ proj_b,
              const short* __restrict__ wT, const short* __restrict__ pT,
              float* __restrict__ out)
{
    __shared__ short smem[23824];
    short* const xs = smem;

    const int b   = blockIdx.x;
    const int tid = threadIdx.x;
    const int wv  = tid >> 6;   // wave 0..5 == head
    const int ln  = tid & 63;
    const int lr  = ln & 15;
    const int lg  = ln >> 4;
    short* const buf = smem + 10000 + wv * 2304;

    // ---------- Phase 1: stage x rows 0..48 -> bf16 LDS, zero row 49 ----------
    {
        const float4* xb4 = reinterpret_cast<const float4*>(x + (long)b * NTOK * DIMC);
        for (int i = tid; i < NTOK * (DIMC / 4); i += 384) {   // 2352 float4s
            const int r = i / (DIMC / 4), c4 = i - r * (DIMC / 4);
            const float4 v = xb4[i];
            short4v s4;
            s4[0] = f2bs(v.x); s4[1] = f2bs(v.y); s4[2] = f2bs(v.z); s4[3] = f2bs(v.w);
            *reinterpret_cast<short4v*>(&xs[r * XP + c4 * 4]) = s4;
        }
        if (tid < 50)  // zero row 49 (the shared pad row)
            *reinterpret_cast<short4v*>(&xs[49 * XP + tid * 4]) = short4v{0, 0, 0, 0};
    }
    __syncthreads();

    const int h = wv;
    // clamped A-row (token) indices: m=3 rows 49..63 read the zero row
    int rowA[4];
    rowA[0] = lr; rowA[1] = 16 + lr; rowA[2] = 32 + lr; rowA[3] = lr ? 49 : 48;

    bf16x8 qa[4], kb[4], vb[2][2];

    // ---------- Phase 2: merged QKV GEMM (q|k|v cols for head h in one pass) ----------
    {
        f32x4 acc[4][6];
        #pragma unroll
        for (int m = 0; m < 4; ++m)
            #pragma unroll
            for (int n = 0; n < 6; ++n) acc[m][n] = f32x4{0.f, 0.f, 0.f, 0.f};
        __builtin_amdgcn_s_setprio(1);
        #pragma unroll
        for (int kk = 0; kk < 6; ++kk) {
            const int k0 = kk * 32 + lg * 8;
            bf16x8 a[4];
            #pragma unroll
            for (int m = 0; m < 4; ++m)
                a[m] = *reinterpret_cast<const bf16x8*>(&xs[rowA[m] * XP + k0]);
            #pragma unroll
            for (int n = 0; n < 6; ++n) {
                // n 0,1 -> q cols ; 2,3 -> k cols ; 4,5 -> v cols (of head h)
                const int cb = (n >> 1) * DIMC + h * HD + (n & 1) * 16 + lr;
                bf16x8 bw = *reinterpret_cast<const bf16x8*>(&wT[cb * DIMC + k0]);
                #pragma unroll
                for (int m = 0; m < 4; ++m)
                    acc[m][n] = __builtin_amdgcn_mfma_f32_16x16x32_bf16(a[m], bw, acc[m][n], 0, 0, 0);
            }
        }
        __builtin_amdgcn_s_setprio(0);

        // q -> buf[64][36] -> qa
        #pragma unroll
        for (int n2 = 0; n2 < 2; ++n2) {
            const float bias = qkv_b[h * HD + n2 * 16 + lr];
            #pragma unroll
            for (int m = 0; m < 4; ++m)
                #pragma unroll
                for (int r = 0; r < 4; ++r)
                    buf[(m * 16 + lg * 4 + r) * QKP + n2 * 16 + lr] = f2bs(acc[m][n2][r] + bias);
        }
        #pragma unroll
        for (int m = 0; m < 4; ++m)
            qa[m] = ld8(&buf[(m * 16 + lr) * QKP + lg * 8]);

        // k -> buf -> kb
        #pragma unroll
        for (int n2 = 0; n2 < 2; ++n2) {
            const float bias = qkv_b[DIMC + h * HD + n2 * 16 + lr];
            #pragma unroll
            for (int m = 0; m < 4; ++m)
                #pragma unroll
                for (int r = 0; r < 4; ++r)
                    buf[(m * 16 + lg * 4 + r) * QKP + n2 * 16 + lr] = f2bs(acc[m][2 + n2][r] + bias);
        }
        #pragma unroll
        for (int m = 0; m < 4; ++m)
            kb[m] = ld8(&buf[(m * 16 + lr) * QKP + lg * 8]);

        // v -> vT [32][68] -> vb
        #pragma unroll
        for (int n2 = 0; n2 < 2; ++n2) {
            const float bias = qkv_b[2 * DIMC + h * HD + n2 * 16 + lr];
            #pragma unroll
            for (int m = 0; m < 4; ++m)
                #pragma unroll
                for (int r = 0; r < 4; ++r)
                    buf[(n2 * 16 + lr) * VP + m * 16 + lg * 4 + r] = f2bs(acc[m][4 + n2][r] + bias);
        }
        #pragma unroll
        for (int kk = 0; kk < 2; ++kk)
            #pragma unroll
            for (int nb = 0; nb < 2; ++nb)
                vb[kk][nb] = ld8(&buf[(nb * 16 + lr) * VP + kk * 32 + lg * 8]);
    }

    // ---------- Phase 3: S = q k^T ----------
    f32x4 s[4][4];
    #pragma unroll
    for (int m = 0; m < 4; ++m)
        #pragma unroll
        for (int n = 0; n < 4; ++n) s[m][n] = f32x4{0.f, 0.f, 0.f, 0.f};
    __builtin_amdgcn_s_setprio(1);
    #pragma unroll
    for (int m = 0; m < 4; ++m)
        #pragma unroll
        for (int n = 0; n < 4; ++n)
            s[m][n] = __builtin_amdgcn_mfma_f32_16x16x32_bf16(qa[m], kb[n], s[m][n], 0, 0, 0);
    __builtin_amdgcn_s_setprio(0);

    // scale + mask + softmax WITHOUT max-subtraction (logits bounded; pad cols -> 0)
    const float* mrow = mask + (long)(b & (NWIN - 1)) * NTOK * NTOK;
    float rinv[4][4];
    #pragma unroll
    for (int m = 0; m < 4; ++m)
        #pragma unroll
        for (int n = 0; n < 4; ++n) {
            const int col = n * 16 + lr;
            #pragma unroll
            for (int r = 0; r < 4; ++r) {
                const int row = m * 16 + lg * 4 + r;
                float v = s[m][n][r];
                v = (row < NTOK && col < NTOK) ? v * SCALE + mrow[row * NTOK + col] : -1e30f;
                s[m][n][r] = __expf(v);
            }
        }
    #pragma unroll
    for (int m = 0; m < 4; ++m)
        #pragma unroll
        for (int r = 0; r < 4; ++r) {
            float sum = s[m][0][r] + s[m][1][r] + s[m][2][r] + s[m][3][r];
            sum += __shfl_xor(sum, 1);
            sum += __shfl_xor(sum, 2);
            sum += __shfl_xor(sum, 4);
            sum += __shfl_xor(sum, 8);
            rinv[m][r] = 1.f / sum;
        }

    // ---------- Phase 4: PV via two P halves in buf [64][36] ----------
    f32x4 o[4][2];
    #pragma unroll
    for (int m = 0; m < 4; ++m)
        #pragma unroll
        for (int n = 0; n < 2; ++n) o[m][n] = f32x4{0.f, 0.f, 0.f, 0.f};
    #pragma unroll
    for (int half = 0; half < 2; ++half) {
        #pragma unroll
        for (int m = 0; m < 4; ++m)
            #pragma unroll
            for (int n2 = 0; n2 < 2; ++n2)
                #pragma unroll
                for (int r = 0; r < 4; ++r)
                    buf[(m * 16 + lg * 4 + r) * QKP + n2 * 16 + lr] = f2bs(s[m][half * 2 + n2][r]);
        bf16x8 pa[4];
        #pragma unroll
        for (int mi = 0; mi < 4; ++mi)
            pa[mi] = ld8(&buf[(mi * 16 + lr) * QKP + lg * 8]);
        __builtin_amdgcn_s_setprio(1);
        #pragma unroll
        for (int nb = 0; nb < 2; ++nb)
            #pragma unroll
            for (int mi = 0; mi < 4; ++mi)
                o[mi][nb] = __builtin_amdgcn_mfma_f32_16x16x32_bf16(pa[mi], vb[half][nb], o[mi][nb], 0, 0, 0);
        __builtin_amdgcn_s_setprio(0);
    }

    __syncthreads();   // all waves done reading xs -> safe to overwrite with attn_out

    // normalize + write attn_out bf16 into xs (cols h*32..h*32+31); pad rows skipped
    #pragma unroll
    for (int nb = 0; nb < 2; ++nb)
        #pragma unroll
        for (int m = 0; m < 4; ++m)
            #pragma unroll
            for (int r = 0; r < 4; ++r) {
                const int row = m * 16 + lg * 4 + r;
                if (row < NTOK)
                    xs[row * XP + h * HD + nb * 16 + lr] = f2bs(o[m][nb][r] * rinv[m][r]);
            }
    __syncthreads();

    // ---------- Phase 5: proj GEMM (wave wv -> out cols [wv*32, wv*32+32)) ----------
    {
        f32x4 acc2[4][2];
        #pragma unroll
        for (int m = 0; m < 4; ++m)
            #pragma unroll
            for (int n = 0; n < 2; ++n) acc2[m][n] = f32x4{0.f, 0.f, 0.f, 0.f};
        const int c0 = wv * 32;
        __builtin_amdgcn_s_setprio(1);
        #pragma unroll
        for (int kk = 0; kk < 6; ++kk) {
            const int k0 = kk * 32 + lg * 8;
            bf16x8 a[4];
            #pragma unroll
            for (int m = 0; m < 4; ++m)
                a[m] = *reinterpret_cast<const bf16x8*>(&xs[rowA[m] * XP + k0]);
            #pragma unroll
            for (int n = 0; n < 2; ++n) {
                bf16x8 bw = *reinterpret_cast<const bf16x8*>(&pT[(c0 + n * 16 + lr) * DIMC + k0]);
                #pragma unroll
                for (int m = 0; m < 4; ++m)
                    acc2[m][n] = __builtin_amdgcn_mfma_f32_16x16x32_bf16(a[m], bw, acc2[m][n], 0, 0, 0);
            }
        }
        __builtin_amdgcn_s_setprio(0);
        float* ob = out + (long)b * NTOK * DIMC;
        #pragma unroll
        for (int n = 0; n < 2; ++n) {
            const int c = c0 + n * 16 + lr;
            const float pb = proj_b[c];
            #pragma unroll
            for (int m = 0; m < 4; ++m)
                #pragma unroll
                for (int r = 0; r < 4; ++r) {
                    const int row = m * 16 + lg * 4 + r;
                    if (row < NTOK) ob[row * DIMC + c] = acc2[m][n][r] + pb;
                }
        }
    }
}

extern "C" void kernel_launch(void* const* d_in, const int* in_sizes, int n_in,
                              void* d_out, int out_size, void* d_ws, size_t ws_size,
                              hipStream_t stream) {
    const float* x      = (const float*)d_in[0];
    const float* mask   = (const float*)d_in[1];
    const float* qkv_w  = (const float*)d_in[2];
    const float* qkv_b  = (const float*)d_in[3];
    const float* proj_w = (const float*)d_in[4];
    const float* proj_b = (const float*)d_in[5];
    float* out = (float*)d_out;

    short* wT = (short*)d_ws;                 // 576*192 bf16
    short* pT = wT + DIMC * 3 * DIMC;         // 192*192 bf16

    const int nwin = in_sizes[0] / (NTOK * DIMC);   // 2048

    prep_weights<<<(DIMC * 3 * DIMC + 255) / 256, 256, 0, stream>>>(qkv_w, proj_w, wT, pT);
    win_attn<<<nwin, 384, 0, stream>>>(x, mask, qkv_b, proj_b, wT, pT, out);
}

// Round 5
// 149.063 us; speedup vs baseline: 1.3708x; 1.3708x over previous
//
#include <hip/hip_runtime.h>

// WindowAttention fused kernel, MI355X gfx950 — round 5.
// Per window b (2048 windows, N=49 tokens, C=192, 6 heads x 32):
//   qkv = x @ qkv_w + b; S = scale*q k^T + mask[b%64]; softmax; o = P v; out = o @ proj_w + b
// 6 waves/block, wave h owns head h end-to-end (R3 structure, no merged-QKV spill).
// R5 changes:
//  - xs pitch 196 (was 200): A-frag b64 banks 2lr-stride -> conflict-free;
//    no zero pad row — pad A-rows clamp to real row 48 (finite copies, masked later).
//  - per-wave scratch 1668 shorts (was 2304): q/k/P [49][34]; vT as two
//    sequential [32][34] halves (vb[kk] read before half kk+1 overwrites).
//    All frag-read strides odd-dword -> conflict-free.
//  - Block LDS 39224 B -> 3 blocks/CU under the observed ~128 KB pool.

#define DIMC 192
#define NHEAD 6
#define HD 32
#define NTOK 49
#define NWIN 64
#define SCALE 0.17677669529663687f  // 1/sqrt(32)
#define XP 196   // xs pitch (shorts), [49][196]
#define SP 34    // scratch pitch (q/k/P transpose and vT halves)
#define WSZ 1668 // per-wave scratch shorts (8B-aligned)

typedef short bf16x8 __attribute__((ext_vector_type(8)));
typedef short bf16x4 __attribute__((ext_vector_type(4)));
typedef short short4v __attribute__((ext_vector_type(4)));
typedef float f32x4 __attribute__((ext_vector_type(4)));

__device__ __forceinline__ short f2bs(float f) {
    // round-to-nearest-even fp32 -> bf16
    unsigned u = __builtin_bit_cast(unsigned, f);
    u = (u + 0x7fffu + ((u >> 16) & 1u)) >> 16;
    return (short)(unsigned short)u;
}

// 8-bf16 fragment load from 8B-aligned LDS
__device__ __forceinline__ bf16x8 ld8(const short* p) {
    bf16x4 lo = *reinterpret_cast<const bf16x4*>(p);
    bf16x4 hi = *reinterpret_cast<const bf16x4*>(p + 4);
    return __builtin_shufflevector(lo, hi, 0, 1, 2, 3, 4, 5, 6, 7);
}

__global__ void prep_weights(const float* __restrict__ qkv_w,
                             const float* __restrict__ proj_w,
                             short* __restrict__ wT, short* __restrict__ pT) {
    int i = blockIdx.x * 256 + threadIdx.x;
    if (i < DIMC * 3 * DIMC) {  // qkv_w [192][576] -> wT [576][192] bf16
        int k = i / (3 * DIMC), c = i - k * (3 * DIMC);
        wT[c * DIMC + k] = f2bs(qkv_w[i]);
    }
    if (i < DIMC * DIMC) {      // proj_w [192][192] -> pT [192][192] bf16 (transposed)
        int k = i / DIMC, c = i - k * DIMC;
        pT[c * DIMC + k] = f2bs(proj_w[i]);
    }
}

// One QKV GEMM chunk: tokens x 32 output cols (c0..c0+31), K=192.
// A rows: {lr, 16+lr, 32+lr, 48(clamped)} — m=3 output = token-48 copies (finite).
__device__ __forceinline__ void qkv_chunk(const short* xs, const short* __restrict__ wT,
                                          int c0, int lr, int lg, const int* rowA,
                                          f32x4 (&acc)[4][2]) {
    #pragma unroll
    for (int m = 0; m < 4; ++m)
        #pragma unroll
        for (int n = 0; n < 2; ++n) acc[m][n] = f32x4{0.f, 0.f, 0.f, 0.f};
    __builtin_amdgcn_s_setprio(1);
    #pragma unroll
    for (int kk = 0; kk < 6; ++kk) {
        const int k0 = kk * 32 + lg * 8;
        bf16x8 a[4];
        #pragma unroll
        for (int m = 0; m < 4; ++m)
            a[m] = ld8(&xs[rowA[m] * XP + k0]);
        #pragma unroll
        for (int n = 0; n < 2; ++n) {
            bf16x8 bw = *reinterpret_cast<const bf16x8*>(&wT[(c0 + n * 16 + lr) * DIMC + k0]);
            #pragma unroll
            for (int m = 0; m < 4; ++m)
                acc[m][n] = __builtin_amdgcn_mfma_f32_16x16x32_bf16(a[m], bw, acc[m][n], 0, 0, 0);
        }
    }
    __builtin_amdgcn_s_setprio(0);
}

// LDS (shorts): xs [49][196] @ 0 (9604) ; per-wave scratch WSZ @ 9604 + wv*WSZ
// total 9604 + 6*1668 = 19612 shorts = 39224 B  => 3 blocks/CU (117.7 KB)

__global__ __launch_bounds__(384, 3)
void win_attn(const float* __restrict__ x, const float* __restrict__ mask,
              const float* __restrict__ qkv_b, const float* __restrict__ proj_b,
              const short* __restrict__ wT, const short* __restrict__ pT,
              float* __restrict__ out)
{
    __shared__ short smem[19612];
    short* const xs = smem;

    const int b   = blockIdx.x;
    const int tid = threadIdx.x;
    const int wv  = tid >> 6;   // wave 0..5 == head
    const int ln  = tid & 63;
    const int lr  = ln & 15;
    const int lg  = ln >> 4;
    short* const buf = smem + 9604 + wv * WSZ;

    // ---------- Phase 1: stage x rows 0..48 -> bf16 LDS ----------
    {
        const float4* xb4 = reinterpret_cast<const float4*>(x + (long)b * NTOK * DIMC);
        for (int i = tid; i < NTOK * (DIMC / 4); i += 384) {   // 2352 float4s
            const int r = i / (DIMC / 4), c4 = i - r * (DIMC / 4);
            const float4 v = xb4[i];
            short4v s4;
            s4[0] = f2bs(v.x); s4[1] = f2bs(v.y); s4[2] = f2bs(v.z); s4[3] = f2bs(v.w);
            *reinterpret_cast<short4v*>(&xs[r * XP + c4 * 4]) = s4;
        }
    }
    __syncthreads();

    const int h = wv;
    int rowA[4];
    rowA[0] = lr; rowA[1] = 16 + lr; rowA[2] = 32 + lr; rowA[3] = 48;  // clamped pad rows

    bf16x8 qa[4], kb[4], vb[2][2];

    // ---------- Phase 2: QKV for own head (3 chunks), transpose via private buf ----------
    {
        f32x4 acc[4][2];
        // q -> buf [49][34] -> qa
        qkv_chunk(xs, wT, h * HD, lr, lg, rowA, acc);
        #pragma unroll
        for (int n2 = 0; n2 < 2; ++n2) {
            const float bias = qkv_b[h * HD + n2 * 16 + lr];
            #pragma unroll
            for (int m = 0; m < 3; ++m)
                #pragma unroll
                for (int r = 0; r < 4; ++r)
                    buf[(m * 16 + lg * 4 + r) * SP + n2 * 16 + lr] = f2bs(acc[m][n2][r] + bias);
            if (lg == 0) buf[48 * SP + n2 * 16 + lr] = f2bs(acc[3][n2][0] + bias);  // row 48
        }
        #pragma unroll
        for (int m = 0; m < 3; ++m)
            qa[m] = ld8(&buf[(m * 16 + lr) * SP + lg * 8]);
        qa[3] = ld8(&buf[48 * SP + lg * 8]);   // rows 48..63 -> token-48 copy (masked later)

        // k -> same buf -> kb
        qkv_chunk(xs, wT, DIMC + h * HD, lr, lg, rowA, acc);
        #pragma unroll
        for (int n2 = 0; n2 < 2; ++n2) {
            const float bias = qkv_b[DIMC + h * HD + n2 * 16 + lr];
            #pragma unroll
            for (int m = 0; m < 3; ++m)
                #pragma unroll
                for (int r = 0; r < 4; ++r)
                    buf[(m * 16 + lg * 4 + r) * SP + n2 * 16 + lr] = f2bs(acc[m][n2][r] + bias);
            if (lg == 0) buf[48 * SP + n2 * 16 + lr] = f2bs(acc[3][n2][0] + bias);
        }
        #pragma unroll
        for (int m = 0; m < 3; ++m)
            kb[m] = ld8(&buf[(m * 16 + lr) * SP + lg * 8]);
        kb[3] = ld8(&buf[48 * SP + lg * 8]);

        // v -> two sequential vT halves [32 d][34] (tokens 0..31, then 32..63)
        qkv_chunk(xs, wT, 2 * DIMC + h * HD, lr, lg, rowA, acc);
        #pragma unroll
        for (int half = 0; half < 2; ++half) {
            #pragma unroll
            for (int n2 = 0; n2 < 2; ++n2) {
                const float bias = qkv_b[2 * DIMC + h * HD + n2 * 16 + lr];
                #pragma unroll
                for (int mm = 0; mm < 2; ++mm) {   // m = half*2 + mm ; local token = mm*16+lg*4+r
                    #pragma unroll
                    for (int r = 0; r < 4; ++r)
                        buf[(n2 * 16 + lr) * SP + mm * 16 + lg * 4 + r] =
                            f2bs(acc[half * 2 + mm][n2][r] + bias);  // pad tokens = finite copies
                }
            }
            #pragma unroll
            for (int nb = 0; nb < 2; ++nb)
                vb[half][nb] = ld8(&buf[(nb * 16 + lr) * SP + lg * 8]);
        }
    }

    // ---------- Phase 3: S = q k^T ----------
    f32x4 s[4][4];
    #pragma unroll
    for (int m = 0; m < 4; ++m)
        #pragma unroll
        for (int n = 0; n < 4; ++n) s[m][n] = f32x4{0.f, 0.f, 0.f, 0.f};
    __builtin_amdgcn_s_setprio(1);
    #pragma unroll
    for (int m = 0; m < 4; ++m)
        #pragma unroll
        for (int n = 0; n < 4; ++n)
            s[m][n] = __builtin_amdgcn_mfma_f32_16x16x32_bf16(qa[m], kb[n], s[m][n], 0, 0, 0);
    __builtin_amdgcn_s_setprio(0);

    // scale + mask + softmax WITHOUT max-subtraction (logits bounded; pads -> exp->0)
    const float* mrow = mask + (long)(b & (NWIN - 1)) * NTOK * NTOK;
    float rinv[4][4];
    #pragma unroll
    for (int m = 0; m < 4; ++m)
        #pragma unroll
        for (int n = 0; n < 4; ++n) {
            const int col = n * 16 + lr;
            #pragma unroll
            for (int r = 0; r < 4; ++r) {
                const int row = m * 16 + lg * 4 + r;
                float v = s[m][n][r];
                v = (row < NTOK && col < NTOK) ? v * SCALE + mrow[row * NTOK + col] : -1e30f;
                s[m][n][r] = __expf(v);
            }
        }
    #pragma unroll
    for (int m = 0; m < 4; ++m)
        #pragma unroll
        for (int r = 0; r < 4; ++r) {
            float sum = s[m][0][r] + s[m][1][r] + s[m][2][r] + s[m][3][r];
            sum += __shfl_xor(sum, 1);
            sum += __shfl_xor(sum, 2);
            sum += __shfl_xor(sum, 4);
            sum += __shfl_xor(sum, 8);
            rinv[m][r] = 1.f / sum;
        }

    // ---------- Phase 4: PV via two P halves in buf [49][34] ----------
    f32x4 o[4][2];
    #pragma unroll
    for (int m = 0; m < 4; ++m)
        #pragma unroll
        for (int n = 0; n < 2; ++n) o[m][n] = f32x4{0.f, 0.f, 0.f, 0.f};
    #pragma unroll
    for (int half = 0; half < 2; ++half) {
        #pragma unroll
        for (int m = 0; m < 3; ++m)
            #pragma unroll
            for (int n2 = 0; n2 < 2; ++n2)
                #pragma unroll
                for (int r = 0; r < 4; ++r)
                    buf[(m * 16 + lg * 4 + r) * SP + n2 * 16 + lr] = f2bs(s[m][half * 2 + n2][r]);
        if (lg == 0) {
            #pragma unroll
            for (int n2 = 0; n2 < 2; ++n2)
                buf[48 * SP + n2 * 16 + lr] = f2bs(s[3][half * 2 + n2][0]);
        }
        bf16x8 pa[4];
        #pragma unroll
        for (int mi = 0; mi < 3; ++mi)
            pa[mi] = ld8(&buf[(mi * 16 + lr) * SP + lg * 8]);
        pa[3] = ld8(&buf[48 * SP + lg * 8]);
        __builtin_amdgcn_s_setprio(1);
        #pragma unroll
        for (int nb = 0; nb < 2; ++nb)
            #pragma unroll
            for (int mi = 0; mi < 4; ++mi)
                o[mi][nb] = __builtin_amdgcn_mfma_f32_16x16x32_bf16(pa[mi], vb[half][nb], o[mi][nb], 0, 0, 0);
        __builtin_amdgcn_s_setprio(0);
    }

    __syncthreads();   // all waves done reading xs -> safe to overwrite with attn_out

    // normalize + write attn_out bf16 into xs (cols h*32..h*32+31); pad rows skipped
    #pragma unroll
    for (int nb = 0; nb < 2; ++nb)
        #pragma unroll
        for (int m = 0; m < 4; ++m)
            #pragma unroll
            for (int r = 0; r < 4; ++r) {
                const int row = m * 16 + lg * 4 + r;
                if (row < NTOK)
                    xs[row * XP + h * HD + nb * 16 + lr] = f2bs(o[m][nb][r] * rinv[m][r]);
            }
    __syncthreads();

    // ---------- Phase 5: proj GEMM (wave wv -> out cols [wv*32, wv*32+32)) ----------
    {
        f32x4 acc2[4][2];
        #pragma unroll
        for (int m = 0; m < 4; ++m)
            #pragma unroll
            for (int n = 0; n < 2; ++n) acc2[m][n] = f32x4{0.f, 0.f, 0.f, 0.f};
        const int c0 = wv * 32;
        __builtin_amdgcn_s_setprio(1);
        #pragma unroll
        for (int kk = 0; kk < 6; ++kk) {
            const int k0 = kk * 32 + lg * 8;
            bf16x8 a[4];
            #pragma unroll
            for (int m = 0; m < 4; ++m)
                a[m] = ld8(&xs[rowA[m] * XP + k0]);
            #pragma unroll
            for (int n = 0; n < 2; ++n) {
                bf16x8 bw = *reinterpret_cast<const bf16x8*>(&pT[(c0 + n * 16 + lr) * DIMC + k0]);
                #pragma unroll
                for (int m = 0; m < 4; ++m)
                    acc2[m][n] = __builtin_amdgcn_mfma_f32_16x16x32_bf16(a[m], bw, acc2[m][n], 0, 0, 0);
            }
        }
        __builtin_amdgcn_s_setprio(0);
        float* ob = out + (long)b * NTOK * DIMC;
        #pragma unroll
        for (int n = 0; n < 2; ++n) {
            const int c = c0 + n * 16 + lr;
            const float pb = proj_b[c];
            #pragma unroll
            for (int m = 0; m < 4; ++m)
                #pragma unroll
                for (int r = 0; r < 4; ++r) {
                    const int row = m * 16 + lg * 4 + r;
                    if (row < NTOK) ob[row * DIMC + c] = acc2[m][n][r] + pb;
                }
        }
    }
}

extern "C" void kernel_launch(void* const* d_in, const int* in_sizes, int n_in,
                              void* d_out, int out_size, void* d_ws, size_t ws_size,
                              hipStream_t stream) {
    const float* x      = (const float*)d_in[0];
    const float* mask   = (const float*)d_in[1];
    const float* qkv_w  = (const float*)d_in[2];
    const float* qkv_b  = (const float*)d_in[3];
    const float* proj_w = (const float*)d_in[4];
    const float* proj_b = (const float*)d_in[5];
    float* out = (float*)d_out;

    short* wT = (short*)d_ws;                 // 576*192 bf16
    short* pT = wT + DIMC * 3 * DIMC;         // 192*192 bf16

    const int nwin = in_sizes[0] / (NTOK * DIMC);   // 2048

    prep_weights<<<(DIMC * 3 * DIMC + 255) / 256, 256, 0, stream>>>(qkv_w, proj_w, wT, pT);
    win_attn<<<nwin, 384, 0, stream>>>(x, mask, qkv_b, proj_b, wT, pT, out);
}